// Round 1
// baseline (729.946 us; speedup 1.0000x reference)
//
#include <hip/hip_runtime.h>
#include <hip/hip_bf16.h>
#include <hip/hip_fp16.h>

using bf16 = __hip_bfloat16;
typedef __attribute__((ext_vector_type(8))) short short8;
typedef __attribute__((ext_vector_type(4))) float f32x4;

static constexpr int Bb = 2, Ss = 1024, Dd = 1024, Ee = 64, Nn = 16;
static constexpr int NBLK = 512;   // 2 blocks/CU guaranteed by __launch_bounds__(256,2)

struct Params {
    const float *X, *posW, *posB, *pbias, *spos, *lsc, *qW, *kW, *vW, *gates, *rwp, *lnw, *lnb;
    bf16 *Xb, *Wt, *WpT, *QKV, *Vt, *Aav;
    __half *wh;
    float *qk[4], *cb[4], *out;
    unsigned *bar;
};

__device__ __forceinline__ unsigned short f2bfr(float f) {
    __hip_bfloat16 h = __float2bfloat16(f);
    return *reinterpret_cast<unsigned short*>(&h);
}

#define GL_LDS(gp, lp) __builtin_amdgcn_global_load_lds( \
    (const __attribute__((address_space(1))) void*)(gp), \
    (__attribute__((address_space(3))) void*)(lp), 16, 0, 0)

// ---------- device-scope grid barrier (all NBLK blocks co-resident) ----------
__device__ __forceinline__ void gridbar(unsigned* bar)
{
    __syncthreads();                       // drains this block's vmem (s_waitcnt vmcnt(0))
    if (threadIdx.x == 0) {
        __threadfence();                   // agent fence: writeback to coherence point
        unsigned g = __hip_atomic_load(&bar[1], __ATOMIC_RELAXED, __HIP_MEMORY_SCOPE_AGENT);
        unsigned old = __hip_atomic_fetch_add(&bar[0], 1u, __ATOMIC_ACQ_REL, __HIP_MEMORY_SCOPE_AGENT);
        if (old == gridDim.x - 1u) {
            __hip_atomic_store(&bar[0], 0u, __ATOMIC_RELAXED, __HIP_MEMORY_SCOPE_AGENT);
            __hip_atomic_store(&bar[1], g + 1u, __ATOMIC_RELEASE, __HIP_MEMORY_SCOPE_AGENT);
        } else {
            while (__hip_atomic_load(&bar[1], __ATOMIC_ACQUIRE, __HIP_MEMORY_SCOPE_AGENT) == g)
                __builtin_amdgcn_s_sleep(2);
        }
        __threadfence();                   // acquire side: invalidate stale lines
    }
    __syncthreads();
}

// ---------- f32 -> bf16 transpose of a 64x64 tile ----------
__device__ __forceinline__ void do_transpose_f2b(
    const float* __restrict__ in, bf16* __restrict__ out,
    int R, int C, int bx, int by, char* sm)
{
    float (*tile)[65] = (float(*)[65])sm;
    int tx = threadIdx.x & 63, ty = threadIdx.x >> 6;
    int r0 = by * 64, c0 = bx * 64;
    #pragma unroll
    for (int i = 0; i < 16; ++i)
        tile[ty + i*4][tx] = in[(long)(r0 + ty + i*4)*C + c0 + tx];
    __syncthreads();
    #pragma unroll
    for (int i = 0; i < 16; ++i)
        out[(long)(c0 + ty + i*4)*R + r0 + tx] = __float2bfloat16(tile[tx][ty + i*4]);
    __syncthreads();
}

// ---------- 64x128 MFMA GEMM tile, BK=64, XOR-swizzled (qk / AV) ----------
__device__ __forceinline__ void do_gemm64(
    const bf16* __restrict__ Ab, const bf16* __restrict__ Bw, float* __restrict__ C,
    int Nc, int m0, int n0, int kBeg, int kEnd, float scale, char* sm)
{
    short* lA = (short*)sm;            // 8 KB
    short* lB = (short*)(sm + 8192);   // 16 KB
    int tid = threadIdx.x, wid = tid >> 6, lane = tid & 63;
    int wn = wid * 32, r16 = lane & 15, quad = lane >> 4;

    f32x4 acc[4][2];
    #pragma unroll
    for (int i = 0; i < 4; ++i)
        #pragma unroll
        for (int j = 0; j < 2; ++j)
            #pragma unroll
            for (int c = 0; c < 4; ++c) acc[i][j][c] = 0.f;

    const short* Ag = (const short*)Ab;
    const short* Bg = (const short*)Bw;

    int arow[2], akg[2], brow[4], bkg[4];
    #pragma unroll
    for (int j = 0; j < 2; ++j) {
        int c = tid + j*256; arow[j] = c >> 3; akg[j] = (c & 7) ^ (arow[j] & 7);
    }
    #pragma unroll
    for (int j = 0; j < 4; ++j) {
        int c = tid + j*256; brow[j] = c >> 3; bkg[j] = (c & 7) ^ (brow[j] & 7);
    }

    for (int k0 = kBeg; k0 < kEnd; k0 += 64) {
        __syncthreads();
        #pragma unroll
        for (int j = 0; j < 2; ++j)
            GL_LDS(Ag + (long)(m0 + arow[j])*1024 + k0 + akg[j]*8, lA + (tid + j*256)*8);
        #pragma unroll
        for (int j = 0; j < 4; ++j)
            GL_LDS(Bg + (long)(n0 + brow[j])*1024 + k0 + bkg[j]*8, lB + (tid + j*256)*8);
        __syncthreads();

        #pragma unroll
        for (int kk = 0; kk < 2; ++kk) {
            int kc = kk*4 + quad;
            short8 af[4], bfv[2];
            #pragma unroll
            for (int i = 0; i < 4; ++i) {
                int r = i*16 + r16;
                af[i] = *(const short8*)(lA + r*64 + (kc ^ (r & 7))*8);
            }
            #pragma unroll
            for (int j = 0; j < 2; ++j) {
                int r = wn + j*16 + r16;
                bfv[j] = *(const short8*)(lB + r*64 + (kc ^ (r & 7))*8);
            }
            #pragma unroll
            for (int i = 0; i < 4; ++i)
                #pragma unroll
                for (int j = 0; j < 2; ++j)
                    acc[i][j] = __builtin_amdgcn_mfma_f32_16x16x32_bf16(af[i], bfv[j], acc[i][j], 0, 0, 0);
        }
    }

    #pragma unroll
    for (int i = 0; i < 4; ++i)
        #pragma unroll
        for (int j = 0; j < 2; ++j)
            #pragma unroll
            for (int rr = 0; rr < 4; ++rr)
                C[(long)(m0 + i*16 + quad*4 + rr)*Nc + n0 + wn + j*16 + r16] =
                    acc[i][j][rr] * scale;
}

// ---------- 128x128 MFMA GEMM tile (m97 structure), BK=64, XOR-swizzled ----------
template<int OUT_MODE>
__device__ __forceinline__ void do_gemm128(
    const bf16* __restrict__ Ab, const bf16* __restrict__ Bw, void* __restrict__ Cv,
    int Nc, int m0, int n0, char* sm)
{
    short* lA = (short*)sm;             // 16 KB
    short* lB = (short*)(sm + 16384);   // 16 KB
    int tid = threadIdx.x, wid = tid >> 6, lane = tid & 63;
    int wm = (wid >> 1) * 64, wnn = (wid & 1) * 64;
    int r16 = lane & 15, quad = lane >> 4;

    f32x4 acc[4][4];
    #pragma unroll
    for (int i = 0; i < 4; ++i)
        #pragma unroll
        for (int j = 0; j < 4; ++j)
            #pragma unroll
            for (int c = 0; c < 4; ++c) acc[i][j][c] = 0.f;

    const short* Ag = (const short*)Ab;
    const short* Bg = (const short*)Bw;

    int rowc[4], kgc[4];
    #pragma unroll
    for (int j = 0; j < 4; ++j) {
        int c = tid + j*256; rowc[j] = c >> 3; kgc[j] = (c & 7) ^ (rowc[j] & 7);
    }

    for (int k0 = 0; k0 < 1024; k0 += 64) {
        __syncthreads();
        #pragma unroll
        for (int j = 0; j < 4; ++j)
            GL_LDS(Ag + (long)(m0 + rowc[j])*1024 + k0 + kgc[j]*8, lA + (tid + j*256)*8);
        #pragma unroll
        for (int j = 0; j < 4; ++j)
            GL_LDS(Bg + (long)(n0 + rowc[j])*1024 + k0 + kgc[j]*8, lB + (tid + j*256)*8);
        __syncthreads();

        #pragma unroll
        for (int kk = 0; kk < 2; ++kk) {
            int kc = kk*4 + quad;
            short8 af[4], bfv[4];
            #pragma unroll
            for (int i = 0; i < 4; ++i) {
                int r = wm + i*16 + r16;
                af[i] = *(const short8*)(lA + r*64 + (kc ^ (r & 7))*8);
            }
            #pragma unroll
            for (int j = 0; j < 4; ++j) {
                int r = wnn + j*16 + r16;
                bfv[j] = *(const short8*)(lB + r*64 + (kc ^ (r & 7))*8);
            }
            #pragma unroll
            for (int i = 0; i < 4; ++i)
                #pragma unroll
                for (int j = 0; j < 4; ++j)
                    acc[i][j] = __builtin_amdgcn_mfma_f32_16x16x32_bf16(af[i], bfv[j], acc[i][j], 0, 0, 0);
        }
    }

    if (OUT_MODE == 1) {
        bf16* C = (bf16*)Cv;
        #pragma unroll
        for (int i = 0; i < 4; ++i)
            #pragma unroll
            for (int j = 0; j < 4; ++j)
                #pragma unroll
                for (int rr = 0; rr < 4; ++rr)
                    C[(long)(m0 + wm + i*16 + quad*4 + rr)*Nc + n0 + wnn + j*16 + r16] =
                        __float2bfloat16(acc[i][j][rr]);
    } else {
        __syncthreads();
        bf16 (*lt)[132] = (bf16(*)[132])sm;   // 33792 B
        #pragma unroll
        for (int i = 0; i < 4; ++i)
            #pragma unroll
            for (int j = 0; j < 4; ++j)
                #pragma unroll
                for (int rr = 0; rr < 4; ++rr)
                    lt[wnn + j*16 + r16][wm + i*16 + quad*4 + rr] =
                        __float2bfloat16(acc[i][j][rr]);
        __syncthreads();
        bf16* Vb = (bf16*)Cv + (long)(m0 >> 10) * Dd * Ss;
        int s0 = m0 & (Ss - 1);
        int colBase = wid * 32 + (lane >> 4);
        int idx = (lane & 15) * 8;
        #pragma unroll
        for (int it = 0; it < 8; ++it) {
            int col = colBase + it * 4;
            ushort4 v0 = *(const ushort4*)&lt[col][idx];
            ushort4 v1 = *(const ushort4*)&lt[col][idx + 4];
            *(ushort4*)(Vb + (long)(n0 + col)*Ss + s0 + idx)     = v0;
            *(ushort4*)(Vb + (long)(n0 + col)*Ss + s0 + idx + 4) = v1;
        }
        __syncthreads();
    }
}

// ---------- pos GEMM (64 rows) + tanh/bias + splat influence -> wh (half) ----------
__device__ __forceinline__ void do_pos(const Params& p, int m0, char* sm)
{
    short* lA = (short*)sm;
    short* lB = (short*)(sm + 4096);
    float (*P)[65]  = (float(*)[65])(sm + 8192);
    float (*sp)[65] = (float(*)[65])(sm + 8192 + 64*65*4);

    int tid = threadIdx.x, wid = tid >> 6, lane = tid & 63;
    int r16 = lane & 15, quad = lane >> 4;

    for (int idx = tid; idx < 16*64; idx += 256)
        sp[idx >> 6][idx & 63] = p.spos[idx];

    f32x4 acc[4];
    #pragma unroll
    for (int j = 0; j < 4; ++j)
        #pragma unroll
        for (int c = 0; c < 4; ++c) acc[j][c] = 0.f;

    int ra = tid >> 2, ka = (tid & 3) * 8;
    const short* Ag = (const short*)p.Xb;
    const short* Bg = (const short*)p.WpT;

    for (int k0 = 0; k0 < Dd; k0 += 32) {
        __syncthreads();
        GL_LDS(Ag + (long)(m0+ra)*1024 + k0 + ka, lA + tid*8);
        GL_LDS(Bg + (long)ra*1024 + k0 + ka,      lB + tid*8);
        __syncthreads();

        short8 af = *(const short8*)(lA + (wid*16 + r16)*32 + quad*8);
        #pragma unroll
        for (int j = 0; j < 4; ++j) {
            short8 bfv = *(const short8*)(lB + (j*16 + r16)*32 + quad*8);
            acc[j] = __builtin_amdgcn_mfma_f32_16x16x32_bf16(af, bfv, acc[j], 0, 0, 0);
        }
    }

    #pragma unroll
    for (int j = 0; j < 4; ++j)
        #pragma unroll
        for (int rr = 0; rr < 4; ++rr) {
            int rl  = wid*16 + quad*4 + rr;
            int col = j*16 + r16;
            int srow = (m0 + rl) & (Ss - 1);
            P[rl][col] = tanhf(acc[j][rr] + p.posB[col]) + p.pbias[srow*Ee + col];
        }
    __syncthreads();

    int n  = tid & 15;
    int rb = (tid >> 4) * 4;
    float sc = __expf(p.lsc[n]);
    sc = fminf(fmaxf(sc, 0.3f), 2.0f);
    float inv2 = -0.5f / (sc * sc);
    #pragma unroll
    for (int rr = 0; rr < 4; ++rr) {
        int row = rb + rr;
        float d2 = 0.f;
        #pragma unroll 16
        for (int e = 0; e < 64; ++e) {
            float df = P[row][e] - sp[n][e];
            d2 += df * df;
        }
        float infl = fmaxf(__expf(d2 * inv2), 0.01f);
        p.wh[(long)(m0 + row)*Nn + n] = __float2half(infl);
    }
    __syncthreads();
}

// ---------- softmax + gated average (LDS f32 row-cache: pass 2 has 0 global reads) ----------
__device__ __forceinline__ void do_softmax(const Params& p, int jb, char* sm)
{
    __half2 (*wt)[9] = (__half2(*)[9])sm;                 // 36864 B
    float (*wi4)[16] = (float(*)[16])(sm + 36864);        //   256 B
    float (*qc)[Ss]  = (float(*)[Ss])(sm + 36864 + 256);  // 16384 B (per-wave row cache)

    int base = (jb & 255) * 4, b = jb >> 8;
    int tid = threadIdx.x, wid = tid >> 6, lane = tid & 63;
    int imax = base + 3;

    const __half*  whb  = p.wh + (long)b*Ss*Nn;
    const __half2* whb2 = (const __half2*)whb;

    __syncthreads();
    for (int j = tid; j <= imax; j += 256) {
        #pragma unroll
        for (int h = 0; h < 8; ++h)
            wt[j][h] = whb2[j*8 + h];
    }
    if (tid < 64) wi4[tid >> 4][tid & 15] =
        __half2float(whb[(long)(base + (tid >> 4))*16 + (tid & 15)]);
    __syncthreads();

    int i = base + wid;
    long roff = ((long)b*Ss + i)*Ss;
    const float* q0 = p.qk[0] + roff;
    const float* q1 = p.qk[1] + roff;
    const float* q2 = p.qk[2] + roff;
    const float* q3 = p.qk[3] + roff;
    bf16* arow      = p.Aav + roff;

    float wiR[16], l[16];
    #pragma unroll
    for (int n = 0; n < 16; ++n) { wiR[n] = wi4[wid][n]; l[n] = 0.f; }

    for (int j = lane; j <= i; j += 64) {
        float q = (q0[j] + q1[j]) + (q2[j] + q3[j]);
        qc[wid][j] = q;
        #pragma unroll
        for (int h = 0; h < 8; ++h) {
            float2 f = __half22float2(wt[j][h]);
            l[2*h]     += __expf(wiR[2*h]     * f.x * q);
            l[2*h + 1] += __expf(wiR[2*h + 1] * f.y * q);
        }
    }
    #pragma unroll
    for (int n = 0; n < 16; ++n)
        #pragma unroll
        for (int off = 32; off > 0; off >>= 1)
            l[n] += __shfl_xor(l[n], off);

    float coef[16];
    #pragma unroll
    for (int n = 0; n < 16; ++n) {
        float g  = p.gates[n];
        float sg = 1.f / (1.f + __expf(-g));
        coef[n]  = sg / (16.f * l[n]);
    }

    for (int j = lane; j < Ss; j += 64) {
        float a = 0.f;
        if (j <= i) {
            float q = qc[wid][j];
            #pragma unroll
            for (int h = 0; h < 8; ++h) {
                float2 f = __half22float2(wt[j][h]);
                a += coef[2*h]     * __expf(wiR[2*h]     * f.x * q);
                a += coef[2*h + 1] * __expf(wiR[2*h + 1] * f.y * q);
            }
        }
        arow[j] = __float2bfloat16(a);
    }
}

// ---------- residual + LayerNorm over 4 cb partials ----------
__device__ __forceinline__ void do_epilogue(const Params& p, long row, char* sm)
{
    float* rs = (float*)sm;
    float* rq = rs + 4;
    int tid = threadIdx.x, wid = tid >> 6, lane = tid & 63;
    float rw = 1.f / (1.f + __expf(-p.rwp[0]));

    __syncthreads();   // protect rs/rq reuse across loop iterations
    int s = (int)(row & (Ss - 1));
    float4 c = ((const float4*)(p.cb[0] + row*Dd))[tid];
    #pragma unroll
    for (int h = 1; h < 4; ++h) {
        if (s >= h*256) {
            float4 ch = ((const float4*)(p.cb[h] + row*Dd))[tid];
            c.x += ch.x; c.y += ch.y; c.z += ch.z; c.w += ch.w;
        }
    }
    float4 xv = ((const float4*)(p.X + row*Dd))[tid];

    float o[4];
    o[0] = rw * xv.x + (1.f - rw) * c.x;
    o[1] = rw * xv.y + (1.f - rw) * c.y;
    o[2] = rw * xv.z + (1.f - rw) * c.z;
    o[3] = rw * xv.w + (1.f - rw) * c.w;

    float sm1 = o[0] + o[1] + o[2] + o[3];
    float sq  = o[0]*o[0] + o[1]*o[1] + o[2]*o[2] + o[3]*o[3];
    #pragma unroll
    for (int off = 32; off > 0; off >>= 1) { sm1 += __shfl_xor(sm1, off); sq += __shfl_xor(sq, off); }
    if (lane == 0) { rs[wid] = sm1; rq[wid] = sq; }
    __syncthreads();
    sm1 = rs[0] + rs[1] + rs[2] + rs[3];
    sq  = rq[0] + rq[1] + rq[2] + rq[3];
    float mu  = sm1 * (1.f/1024.f);
    float var = sq * (1.f/1024.f) - mu*mu;
    float inv = rsqrtf(var + 1e-5f);

    float4 lw = ((const float4*)p.lnw)[tid];
    float4 lb = ((const float4*)p.lnb)[tid];
    float4 y;
    y.x = (o[0] - mu)*inv*lw.x + lb.x;
    y.y = (o[1] - mu)*inv*lw.y + lb.y;
    y.z = (o[2] - mu)*inv*lw.z + lb.z;
    y.w = (o[3] - mu)*inv*lw.w + lb.w;
    ((float4*)(p.out + row*Dd))[tid] = y;
}

// ========== the whole pipeline: 1 kernel, 6 phases, 5 grid barriers ==========
__global__ __launch_bounds__(256, 2) void k_mega(Params p)
{
    __shared__ __align__(16) char sm[53504];

    // ---- P0: weight transposes + posW^T + X cast (1024 jobs) ----
    for (int j = blockIdx.x; j < 1024; j += NBLK) {
        int x = j & 15, y = (j >> 4) & 15, z = j >> 8;
        if (z < 3) {
            const float* w = (z == 0) ? p.qW : (z == 1) ? p.kW : p.vW;
            do_transpose_f2b(w, p.Wt + (long)z*Dd*Dd, Dd, Dd, x, y, sm);
        } else if (x == 0) {
            do_transpose_f2b(p.posW, p.WpT, Dd, Ee, 0, y, sm);
        } else {
            int job = y * 15 + (x - 1);                 // 0..239
            const float4* src = (const float4*)p.X;
            ushort4* dst = (ushort4*)p.Xb;
            for (int idx = job*256 + (int)threadIdx.x; idx < Bb*Ss*Dd/4; idx += 240*256) {
                float4 v = src[idx];
                ushort4 yv;
                yv.x = f2bfr(v.x); yv.y = f2bfr(v.y); yv.z = f2bfr(v.z); yv.w = f2bfr(v.w);
                dst[idx] = yv;
            }
        }
    }
    gridbar(p.bar);

    // ---- P1: QKV GEMM 128x128 (384 jobs; V transposed) + pos (32 jobs) ----
    for (int j = blockIdx.x; j < 416; j += NBLK) {
        if (j < 384) {
            int z = j >> 7, t = j & 127;
            int bm = t >> 3, bn = t & 7;
            if (z < 2)
                do_gemm128<1>(p.Xb, p.Wt + (long)z*Dd*Dd, p.QKV + (long)z*2048*1024,
                              Dd, bm*128, bn*128, sm);
            else
                do_gemm128<2>(p.Xb, p.Wt + (long)2*Dd*Dd, p.Vt,
                              Dd, bm*128, bn*128, sm);
        } else {
            do_pos(p, (j - 384)*64, sm);
        }
    }
    gridbar(p.bar);

    // ---- P2: qk split-K=4 (576 jobs) ----
    for (int j = blockIdx.x; j < 576; j += NBLK) {
        int h = j & 3, pairIdx = j >> 2;
        int b = pairIdx / 72, t = pairIdx % 72;
        int acc = 0, bm = 0, bn = 0;
        #pragma unroll
        for (int u = 0; u < 16; ++u) {
            int c = (u >> 1) + 1;
            if (t < acc + c) { bm = u; bn = t - acc; break; }
            acc += c;
        }
        const bf16* Qb = p.QKV + (long)b*Ss*Dd;
        const bf16* Kb = p.QKV + (long)2048*1024 + (long)b*Ss*Dd;
        float* dst = p.qk[h] + (long)b*Ss*Ss;
        do_gemm64(Qb, Kb, dst, Ss, bm*64, bn*128, h*256, h*256 + 256, 0.03125f, sm);
    }
    gridbar(p.bar);

    // ---- P3: softmax + gated average (512 jobs) ----
    for (int j = blockIdx.x; j < 512; j += NBLK)
        do_softmax(p, j, sm);
    gridbar(p.bar);

    // ---- P4: AV GEMM split-K<=4 (640 jobs) ----
    for (int j = blockIdx.x; j < 640; j += NBLK) {
        int b  = j / 320;
        int r  = j % 320;
        int bn = r / 40;
        int u  = r % 40;
        int acc = 0, bm = 0, h = 0;
        #pragma unroll
        for (int m = 0; m < 16; ++m) {
            int c = (m >> 2) + 1;
            if (u < acc + c) { bm = m; h = u - acc; break; }
            acc += c;
        }
        int kBeg = h * 256;
        int kEnd = (bm + 1) * 64; if (kEnd > kBeg + 256) kEnd = kBeg + 256;

        const bf16* Ab = p.Aav + (long)b*Ss*Ss;
        const bf16* Bw = p.Vt + (long)b*Dd*Ss;
        float* dst = p.cb[h] + (long)b*Ss*Dd;
        do_gemm64(Ab, Bw, dst, Dd, bm*64, bn*128, kBeg, kEnd, 1.f, sm);
    }
    gridbar(p.bar);

    // ---- P5: residual + LayerNorm (2048 jobs) ----
    for (int j = blockIdx.x; j < 2048; j += NBLK)
        do_epilogue(p, (long)j, sm);
}

extern "C" void kernel_launch(void* const* d_in, const int* in_sizes, int n_in,
                              void* d_out, int out_size, void* d_ws, size_t ws_size,
                              hipStream_t stream)
{
    Params prm;
    prm.X     = (const float*)d_in[0];
    prm.posW  = (const float*)d_in[1];
    prm.posB  = (const float*)d_in[2];
    prm.pbias = (const float*)d_in[3];
    prm.spos  = (const float*)d_in[4];
    prm.lsc   = (const float*)d_in[5];
    prm.qW    = (const float*)d_in[6];
    prm.kW    = (const float*)d_in[7];
    prm.vW    = (const float*)d_in[8];
    prm.gates = (const float*)d_in[9];
    prm.rwp   = (const float*)d_in[10];
    prm.lnw   = (const float*)d_in[11];
    prm.lnb   = (const float*)d_in[12];

    char* ws = (char*)d_ws;
    size_t off = 0;
    prm.Xb  = (bf16*)(ws + off);   off += (size_t)Bb*Ss*Dd*2;
    prm.Wt  = (bf16*)(ws + off);   off += (size_t)3*Dd*Dd*2;
    prm.WpT = (bf16*)(ws + off);   off += (size_t)Ee*Dd*2;
    prm.QKV = (bf16*)(ws + off);   off += (size_t)2*2048*1024*2;  // Q,K only (V -> Vt)
    prm.Vt  = (bf16*)(ws + off);   off += (size_t)Bb*Dd*Ss*2;
    prm.Aav = (bf16*)(ws + off);   off += (size_t)Bb*Ss*Ss*2;
    prm.wh  = (__half*)(ws + off); off += (size_t)Bb*Ss*Nn*2;
    for (int h = 0; h < 4; ++h) { prm.qk[h] = (float*)(ws + off); off += (size_t)Bb*Ss*Ss*4; }
    for (int h = 0; h < 4; ++h) { prm.cb[h] = (float*)(ws + off); off += (size_t)Bb*Ss*Dd*4; }
    prm.bar = (unsigned*)(ws + off); off += 128;
    prm.out = (float*)d_out;
    (void)ws_size;

    // barrier state must be zeroed every call (workspace is re-poisoned between runs)
    hipMemsetAsync(prm.bar, 0, 16, stream);
    k_mega<<<NBLK, 256, 0, stream>>>(prm);
}

// Round 2
// 423.175 us; speedup vs baseline: 1.7249x; 1.7249x over previous
//
#include <hip/hip_runtime.h>
#include <hip/hip_bf16.h>
#include <hip/hip_fp16.h>

using bf16 = __hip_bfloat16;
typedef __attribute__((ext_vector_type(8))) short short8;
typedef __attribute__((ext_vector_type(4))) float f32x4;

static constexpr int Bb = 2, Ss = 1024, Dd = 1024, Ee = 64, Nn = 16;
static constexpr int NBLK = 1024;   // 4 blocks/CU guaranteed: VGPR<=128 (bounds), LDS 37376*4 <= 160K

struct Params {
    const float *X, *posW, *posB, *pbias, *spos, *lsc, *qW, *kW, *vW, *gates, *rwp, *lnw, *lnb;
    bf16 *Xb, *Wt, *WpT, *QKV, *Vt, *Aav;
    __half *wh;
    float *qk[4], *cb[4], *out;
    unsigned *bar;
};

__device__ __forceinline__ unsigned short f2bfr(float f) {
    __hip_bfloat16 h = __float2bfloat16(f);
    return *reinterpret_cast<unsigned short*>(&h);
}

#define GL_LDS(gp, lp) __builtin_amdgcn_global_load_lds( \
    (const __attribute__((address_space(1))) void*)(gp), \
    (__attribute__((address_space(3))) void*)(lp), 16, 0, 0)

// ---------- hierarchical grid barrier: relaxed polls, one acquire fence ----------
// bar layout (u32 indices): leaf i at [i*16] (64B stride, 32 leaves),
// root at [512], epoch at [544]. All blocks co-resident by construction.
__device__ __forceinline__ void gridbar(unsigned* bar)
{
    __syncthreads();
    if (threadIdx.x == 0) {
        __threadfence();   // release: write back this block's stores past L2
        unsigned g = __hip_atomic_load(&bar[544], __ATOMIC_RELAXED, __HIP_MEMORY_SCOPE_AGENT);
        unsigned* lc = &bar[(blockIdx.x & 31u) * 16u];
        unsigned mem = gridDim.x >> 5;   // members per leaf (grid divisible by 32)
        unsigned lo = __hip_atomic_fetch_add(lc, 1u, __ATOMIC_RELAXED, __HIP_MEMORY_SCOPE_AGENT);
        if (lo == mem - 1u) {
            __hip_atomic_store(lc, 0u, __ATOMIC_RELAXED, __HIP_MEMORY_SCOPE_AGENT);
            unsigned ro = __hip_atomic_fetch_add(&bar[512], 1u, __ATOMIC_RELAXED, __HIP_MEMORY_SCOPE_AGENT);
            if (ro == 31u) {
                __hip_atomic_store(&bar[512], 0u, __ATOMIC_RELAXED, __HIP_MEMORY_SCOPE_AGENT);
                __hip_atomic_store(&bar[544], g + 1u, __ATOMIC_RELEASE, __HIP_MEMORY_SCOPE_AGENT);
            }
        }
        while (__hip_atomic_load(&bar[544], __ATOMIC_RELAXED, __HIP_MEMORY_SCOPE_AGENT) == g)
            __builtin_amdgcn_s_sleep(2);   // relaxed poll: no per-poll cache invalidate
        __threadfence();   // acquire: invalidate stale lines once
    }
    __syncthreads();
}

// ---------- f32 -> bf16 transpose of a 64x64 tile ----------
__device__ __forceinline__ void do_transpose_f2b(
    const float* __restrict__ in, bf16* __restrict__ out,
    int R, int C, int bx, int by, char* sm)
{
    float (*tile)[65] = (float(*)[65])sm;
    int tx = threadIdx.x & 63, ty = threadIdx.x >> 6;
    int r0 = by * 64, c0 = bx * 64;
    #pragma unroll
    for (int i = 0; i < 16; ++i)
        tile[ty + i*4][tx] = in[(long)(r0 + ty + i*4)*C + c0 + tx];
    __syncthreads();
    #pragma unroll
    for (int i = 0; i < 16; ++i)
        out[(long)(c0 + ty + i*4)*R + r0 + tx] = __float2bfloat16(tile[tx][ty + i*4]);
    __syncthreads();
}

// ---------- 64x128 MFMA GEMM tile, BK=64, XOR-swizzled (qk / AV) ----------
__device__ __forceinline__ void do_gemm64(
    const bf16* __restrict__ Ab, const bf16* __restrict__ Bw, float* __restrict__ C,
    int Nc, int m0, int n0, int kBeg, int kEnd, float scale, char* sm)
{
    short* lA = (short*)sm;            // 8 KB
    short* lB = (short*)(sm + 8192);   // 16 KB
    int tid = threadIdx.x, wid = tid >> 6, lane = tid & 63;
    int wn = wid * 32, r16 = lane & 15, quad = lane >> 4;

    f32x4 acc[4][2];
    #pragma unroll
    for (int i = 0; i < 4; ++i)
        #pragma unroll
        for (int j = 0; j < 2; ++j)
            #pragma unroll
            for (int c = 0; c < 4; ++c) acc[i][j][c] = 0.f;

    const short* Ag = (const short*)Ab;
    const short* Bg = (const short*)Bw;

    int arow[2], akg[2], brow[4], bkg[4];
    #pragma unroll
    for (int j = 0; j < 2; ++j) {
        int c = tid + j*256; arow[j] = c >> 3; akg[j] = (c & 7) ^ (arow[j] & 7);
    }
    #pragma unroll
    for (int j = 0; j < 4; ++j) {
        int c = tid + j*256; brow[j] = c >> 3; bkg[j] = (c & 7) ^ (brow[j] & 7);
    }

    for (int k0 = kBeg; k0 < kEnd; k0 += 64) {
        __syncthreads();
        #pragma unroll
        for (int j = 0; j < 2; ++j)
            GL_LDS(Ag + (long)(m0 + arow[j])*1024 + k0 + akg[j]*8, lA + (tid + j*256)*8);
        #pragma unroll
        for (int j = 0; j < 4; ++j)
            GL_LDS(Bg + (long)(n0 + brow[j])*1024 + k0 + bkg[j]*8, lB + (tid + j*256)*8);
        __syncthreads();

        #pragma unroll
        for (int kk = 0; kk < 2; ++kk) {
            int kc = kk*4 + quad;
            short8 af[4], bfv[2];
            #pragma unroll
            for (int i = 0; i < 4; ++i) {
                int r = i*16 + r16;
                af[i] = *(const short8*)(lA + r*64 + (kc ^ (r & 7))*8);
            }
            #pragma unroll
            for (int j = 0; j < 2; ++j) {
                int r = wn + j*16 + r16;
                bfv[j] = *(const short8*)(lB + r*64 + (kc ^ (r & 7))*8);
            }
            #pragma unroll
            for (int i = 0; i < 4; ++i)
                #pragma unroll
                for (int j = 0; j < 2; ++j)
                    acc[i][j] = __builtin_amdgcn_mfma_f32_16x16x32_bf16(af[i], bfv[j], acc[i][j], 0, 0, 0);
        }
    }

    #pragma unroll
    for (int i = 0; i < 4; ++i)
        #pragma unroll
        for (int j = 0; j < 2; ++j)
            #pragma unroll
            for (int rr = 0; rr < 4; ++rr)
                C[(long)(m0 + i*16 + quad*4 + rr)*Nc + n0 + wn + j*16 + r16] =
                    acc[i][j][rr] * scale;
}

// ---------- 128x128 MFMA GEMM tile (m97 structure), BK=64, XOR-swizzled ----------
template<int OUT_MODE>
__device__ __forceinline__ void do_gemm128(
    const bf16* __restrict__ Ab, const bf16* __restrict__ Bw, void* __restrict__ Cv,
    int Nc, int m0, int n0, char* sm)
{
    short* lA = (short*)sm;             // 16 KB
    short* lB = (short*)(sm + 16384);   // 16 KB
    int tid = threadIdx.x, wid = tid >> 6, lane = tid & 63;
    int wm = (wid >> 1) * 64, wnn = (wid & 1) * 64;
    int r16 = lane & 15, quad = lane >> 4;

    f32x4 acc[4][4];
    #pragma unroll
    for (int i = 0; i < 4; ++i)
        #pragma unroll
        for (int j = 0; j < 4; ++j)
            #pragma unroll
            for (int c = 0; c < 4; ++c) acc[i][j][c] = 0.f;

    const short* Ag = (const short*)Ab;
    const short* Bg = (const short*)Bw;

    int rowc[4], kgc[4];
    #pragma unroll
    for (int j = 0; j < 4; ++j) {
        int c = tid + j*256; rowc[j] = c >> 3; kgc[j] = (c & 7) ^ (rowc[j] & 7);
    }

    for (int k0 = 0; k0 < 1024; k0 += 64) {
        __syncthreads();
        #pragma unroll
        for (int j = 0; j < 4; ++j)
            GL_LDS(Ag + (long)(m0 + rowc[j])*1024 + k0 + kgc[j]*8, lA + (tid + j*256)*8);
        #pragma unroll
        for (int j = 0; j < 4; ++j)
            GL_LDS(Bg + (long)(n0 + rowc[j])*1024 + k0 + kgc[j]*8, lB + (tid + j*256)*8);
        __syncthreads();

        #pragma unroll
        for (int kk = 0; kk < 2; ++kk) {
            int kc = kk*4 + quad;
            short8 af[4], bfv[4];
            #pragma unroll
            for (int i = 0; i < 4; ++i) {
                int r = wm + i*16 + r16;
                af[i] = *(const short8*)(lA + r*64 + (kc ^ (r & 7))*8);
            }
            #pragma unroll
            for (int j = 0; j < 4; ++j) {
                int r = wnn + j*16 + r16;
                bfv[j] = *(const short8*)(lB + r*64 + (kc ^ (r & 7))*8);
            }
            #pragma unroll
            for (int i = 0; i < 4; ++i)
                #pragma unroll
                for (int j = 0; j < 4; ++j)
                    acc[i][j] = __builtin_amdgcn_mfma_f32_16x16x32_bf16(af[i], bfv[j], acc[i][j], 0, 0, 0);
        }
    }

    if (OUT_MODE == 1) {
        bf16* C = (bf16*)Cv;
        #pragma unroll
        for (int i = 0; i < 4; ++i)
            #pragma unroll
            for (int j = 0; j < 4; ++j)
                #pragma unroll
                for (int rr = 0; rr < 4; ++rr)
                    C[(long)(m0 + wm + i*16 + quad*4 + rr)*Nc + n0 + wnn + j*16 + r16] =
                        __float2bfloat16(acc[i][j][rr]);
    } else {
        __syncthreads();
        bf16 (*lt)[132] = (bf16(*)[132])sm;   // 33792 B
        #pragma unroll
        for (int i = 0; i < 4; ++i)
            #pragma unroll
            for (int j = 0; j < 4; ++j)
                #pragma unroll
                for (int rr = 0; rr < 4; ++rr)
                    lt[wnn + j*16 + r16][wm + i*16 + quad*4 + rr] =
                        __float2bfloat16(acc[i][j][rr]);
        __syncthreads();
        bf16* Vb = (bf16*)Cv + (long)(m0 >> 10) * Dd * Ss;
        int s0 = m0 & (Ss - 1);
        int colBase = wid * 32 + (lane >> 4);
        int idx = (lane & 15) * 8;
        #pragma unroll
        for (int it = 0; it < 8; ++it) {
            int col = colBase + it * 4;
            ushort4 v0 = *(const ushort4*)&lt[col][idx];
            ushort4 v1 = *(const ushort4*)&lt[col][idx + 4];
            *(ushort4*)(Vb + (long)(n0 + col)*Ss + s0 + idx)     = v0;
            *(ushort4*)(Vb + (long)(n0 + col)*Ss + s0 + idx + 4) = v1;
        }
        __syncthreads();
    }
}

// ---------- pos GEMM (64 rows) + tanh/bias + splat influence -> wh (half) ----------
__device__ __forceinline__ void do_pos(const Params& p, int m0, char* sm)
{
    short* lA = (short*)sm;
    short* lB = (short*)(sm + 4096);
    float (*P)[65]  = (float(*)[65])(sm + 8192);
    float (*sp)[65] = (float(*)[65])(sm + 8192 + 64*65*4);

    int tid = threadIdx.x, wid = tid >> 6, lane = tid & 63;
    int r16 = lane & 15, quad = lane >> 4;

    for (int idx = tid; idx < 16*64; idx += 256)
        sp[idx >> 6][idx & 63] = p.spos[idx];

    f32x4 acc[4];
    #pragma unroll
    for (int j = 0; j < 4; ++j)
        #pragma unroll
        for (int c = 0; c < 4; ++c) acc[j][c] = 0.f;

    int ra = tid >> 2, ka = (tid & 3) * 8;
    const short* Ag = (const short*)p.Xb;
    const short* Bg = (const short*)p.WpT;

    for (int k0 = 0; k0 < Dd; k0 += 32) {
        __syncthreads();
        GL_LDS(Ag + (long)(m0+ra)*1024 + k0 + ka, lA + tid*8);
        GL_LDS(Bg + (long)ra*1024 + k0 + ka,      lB + tid*8);
        __syncthreads();

        short8 af = *(const short8*)(lA + (wid*16 + r16)*32 + quad*8);
        #pragma unroll
        for (int j = 0; j < 4; ++j) {
            short8 bfv = *(const short8*)(lB + (j*16 + r16)*32 + quad*8);
            acc[j] = __builtin_amdgcn_mfma_f32_16x16x32_bf16(af, bfv, acc[j], 0, 0, 0);
        }
    }

    #pragma unroll
    for (int j = 0; j < 4; ++j)
        #pragma unroll
        for (int rr = 0; rr < 4; ++rr) {
            int rl  = wid*16 + quad*4 + rr;
            int col = j*16 + r16;
            int srow = (m0 + rl) & (Ss - 1);
            P[rl][col] = tanhf(acc[j][rr] + p.posB[col]) + p.pbias[srow*Ee + col];
        }
    __syncthreads();

    int n  = tid & 15;
    int rb = (tid >> 4) * 4;
    float sc = __expf(p.lsc[n]);
    sc = fminf(fmaxf(sc, 0.3f), 2.0f);
    float inv2 = -0.5f / (sc * sc);
    #pragma unroll
    for (int rr = 0; rr < 4; ++rr) {
        int row = rb + rr;
        float d2 = 0.f;
        #pragma unroll 16
        for (int e = 0; e < 64; ++e) {
            float df = P[row][e] - sp[n][e];
            d2 += df * df;
        }
        float infl = fmaxf(__expf(d2 * inv2), 0.01f);
        p.wh[(long)(m0 + row)*Nn + n] = __float2half(infl);
    }
    __syncthreads();
}

// ---------- softmax + gated average over 4 qk partials (round-0 proven version) ----------
__device__ __forceinline__ void do_softmax(const Params& p, int jb, char* sm)
{
    __half2 (*wt)[9] = (__half2(*)[9])sm;                 // 36864 B
    float (*wi4)[16] = (float(*)[16])(sm + 36864);        //   256 B

    int base = (jb & 255) * 4, b = jb >> 8;
    int tid = threadIdx.x, wid = tid >> 6, lane = tid & 63;
    int imax = base + 3;

    const __half*  whb  = p.wh + (long)b*Ss*Nn;
    const __half2* whb2 = (const __half2*)whb;

    __syncthreads();
    for (int j = tid; j <= imax; j += 256) {
        #pragma unroll
        for (int h = 0; h < 8; ++h)
            wt[j][h] = whb2[j*8 + h];
    }
    if (tid < 64) wi4[tid >> 4][tid & 15] =
        __half2float(whb[(long)(base + (tid >> 4))*16 + (tid & 15)]);
    __syncthreads();

    int i = base + wid;
    long roff = ((long)b*Ss + i)*Ss;
    const float* q0 = p.qk[0] + roff;
    const float* q1 = p.qk[1] + roff;
    const float* q2 = p.qk[2] + roff;
    const float* q3 = p.qk[3] + roff;
    bf16* arow      = p.Aav + roff;

    float wiR[16], l[16];
    #pragma unroll
    for (int n = 0; n < 16; ++n) { wiR[n] = wi4[wid][n]; l[n] = 0.f; }

    for (int j = lane; j <= i; j += 64) {
        float q = (q0[j] + q1[j]) + (q2[j] + q3[j]);
        #pragma unroll
        for (int h = 0; h < 8; ++h) {
            float2 f = __half22float2(wt[j][h]);
            l[2*h]     += __expf(wiR[2*h]     * f.x * q);
            l[2*h + 1] += __expf(wiR[2*h + 1] * f.y * q);
        }
    }
    #pragma unroll
    for (int n = 0; n < 16; ++n)
        #pragma unroll
        for (int off = 32; off > 0; off >>= 1)
            l[n] += __shfl_xor(l[n], off);

    float coef[16];
    #pragma unroll
    for (int n = 0; n < 16; ++n) {
        float g  = p.gates[n];
        float sg = 1.f / (1.f + __expf(-g));
        coef[n]  = sg / (16.f * l[n]);
    }

    for (int j = lane; j < Ss; j += 64) {
        float a = 0.f;
        if (j <= i) {
            float q = (q0[j] + q1[j]) + (q2[j] + q3[j]);
            #pragma unroll
            for (int h = 0; h < 8; ++h) {
                float2 f = __half22float2(wt[j][h]);
                a += coef[2*h]     * __expf(wiR[2*h]     * f.x * q);
                a += coef[2*h + 1] * __expf(wiR[2*h + 1] * f.y * q);
            }
        }
        arow[j] = __float2bfloat16(a);
    }
}

// ---------- residual + LayerNorm over 4 cb partials ----------
__device__ __forceinline__ void do_epilogue(const Params& p, long row, char* sm)
{
    float* rs = (float*)sm;
    float* rq = rs + 4;
    int tid = threadIdx.x, wid = tid >> 6, lane = tid & 63;
    float rw = 1.f / (1.f + __expf(-p.rwp[0]));

    __syncthreads();   // protect rs/rq reuse across loop iterations
    int s = (int)(row & (Ss - 1));
    float4 c = ((const float4*)(p.cb[0] + row*Dd))[tid];
    #pragma unroll
    for (int h = 1; h < 4; ++h) {
        if (s >= h*256) {
            float4 ch = ((const float4*)(p.cb[h] + row*Dd))[tid];
            c.x += ch.x; c.y += ch.y; c.z += ch.z; c.w += ch.w;
        }
    }
    float4 xv = ((const float4*)(p.X + row*Dd))[tid];

    float o[4];
    o[0] = rw * xv.x + (1.f - rw) * c.x;
    o[1] = rw * xv.y + (1.f - rw) * c.y;
    o[2] = rw * xv.z + (1.f - rw) * c.z;
    o[3] = rw * xv.w + (1.f - rw) * c.w;

    float sm1 = o[0] + o[1] + o[2] + o[3];
    float sq  = o[0]*o[0] + o[1]*o[1] + o[2]*o[2] + o[3]*o[3];
    #pragma unroll
    for (int off = 32; off > 0; off >>= 1) { sm1 += __shfl_xor(sm1, off); sq += __shfl_xor(sq, off); }
    if (lane == 0) { rs[wid] = sm1; rq[wid] = sq; }
    __syncthreads();
    sm1 = rs[0] + rs[1] + rs[2] + rs[3];
    sq  = rq[0] + rq[1] + rq[2] + rq[3];
    float mu  = sm1 * (1.f/1024.f);
    float var = sq * (1.f/1024.f) - mu*mu;
    float inv = rsqrtf(var + 1e-5f);

    float4 lw = ((const float4*)p.lnw)[tid];
    float4 lb = ((const float4*)p.lnb)[tid];
    float4 y;
    y.x = (o[0] - mu)*inv*lw.x + lb.x;
    y.y = (o[1] - mu)*inv*lw.y + lb.y;
    y.z = (o[2] - mu)*inv*lw.z + lb.z;
    y.w = (o[3] - mu)*inv*lw.w + lb.w;
    ((float4*)(p.out + row*Dd))[tid] = y;
}

// ========== whole pipeline: 1 kernel, 6 phases, 5 grid barriers ==========
// grid=1024: every phase has <=1 job/block (epilogue: 2) -> no stragglers.
__global__ __launch_bounds__(256, 4) void k_mega(Params p)
{
    __shared__ __align__(16) char sm[37120];   // max user: softmax 37120; 4 blocks/CU fits 160K

    // ---- P0: weight transposes + posW^T + X cast (1024 jobs) ----
    for (int j = blockIdx.x; j < 1024; j += NBLK) {
        int x = j & 15, y = (j >> 4) & 15, z = j >> 8;
        if (z < 3) {
            const float* w = (z == 0) ? p.qW : (z == 1) ? p.kW : p.vW;
            do_transpose_f2b(w, p.Wt + (long)z*Dd*Dd, Dd, Dd, x, y, sm);
        } else if (x == 0) {
            do_transpose_f2b(p.posW, p.WpT, Dd, Ee, 0, y, sm);
        } else {
            int job = y * 15 + (x - 1);                 // 0..239
            const float4* src = (const float4*)p.X;
            ushort4* dst = (ushort4*)p.Xb;
            for (int idx = job*256 + (int)threadIdx.x; idx < Bb*Ss*Dd/4; idx += 240*256) {
                float4 v = src[idx];
                ushort4 yv;
                yv.x = f2bfr(v.x); yv.y = f2bfr(v.y); yv.z = f2bfr(v.z); yv.w = f2bfr(v.w);
                dst[idx] = yv;
            }
        }
    }
    gridbar(p.bar);

    // ---- P1: QKV GEMM 128x128 (384 jobs; V transposed) + pos (32 jobs) ----
    for (int j = blockIdx.x; j < 416; j += NBLK) {
        if (j < 384) {
            int z = j >> 7, t = j & 127;
            int bm = t >> 3, bn = t & 7;
            if (z < 2)
                do_gemm128<1>(p.Xb, p.Wt + (long)z*Dd*Dd, p.QKV + (long)z*2048*1024,
                              Dd, bm*128, bn*128, sm);
            else
                do_gemm128<2>(p.Xb, p.Wt + (long)2*Dd*Dd, p.Vt,
                              Dd, bm*128, bn*128, sm);
        } else {
            do_pos(p, (j - 384)*64, sm);
        }
    }
    gridbar(p.bar);

    // ---- P2: qk split-K=4 (576 jobs) ----
    for (int j = blockIdx.x; j < 576; j += NBLK) {
        int h = j & 3, pairIdx = j >> 2;
        int b = pairIdx / 72, t = pairIdx % 72;
        int acc = 0, bm = 0, bn = 0;
        #pragma unroll
        for (int u = 0; u < 16; ++u) {
            int c = (u >> 1) + 1;
            if (t < acc + c) { bm = u; bn = t - acc; break; }
            acc += c;
        }
        const bf16* Qb = p.QKV + (long)b*Ss*Dd;
        const bf16* Kb = p.QKV + (long)2048*1024 + (long)b*Ss*Dd;
        float* dst = p.qk[h] + (long)b*Ss*Ss;
        do_gemm64(Qb, Kb, dst, Ss, bm*64, bn*128, h*256, h*256 + 256, 0.03125f, sm);
    }
    gridbar(p.bar);

    // ---- P3: softmax + gated average (512 jobs) ----
    for (int j = blockIdx.x; j < 512; j += NBLK)
        do_softmax(p, j, sm);
    gridbar(p.bar);

    // ---- P4: AV GEMM split-K<=4 (640 jobs) ----
    for (int j = blockIdx.x; j < 640; j += NBLK) {
        int b  = j / 320;
        int r  = j % 320;
        int bn = r / 40;
        int u  = r % 40;
        int acc = 0, bm = 0, h = 0;
        #pragma unroll
        for (int m = 0; m < 16; ++m) {
            int c = (m >> 2) + 1;
            if (u < acc + c) { bm = m; h = u - acc; break; }
            acc += c;
        }
        int kBeg = h * 256;
        int kEnd = (bm + 1) * 64; if (kEnd > kBeg + 256) kEnd = kBeg + 256;

        const bf16* Ab = p.Aav + (long)b*Ss*Ss;
        const bf16* Bw = p.Vt + (long)b*Dd*Ss;
        float* dst = p.cb[h] + (long)b*Ss*Dd;
        do_gemm64(Ab, Bw, dst, Dd, bm*64, bn*128, kBeg, kEnd, 1.f, sm);
    }
    gridbar(p.bar);

    // ---- P5: residual + LayerNorm (2048 jobs, 2/block) ----
    for (int j = blockIdx.x; j < 2048; j += NBLK)
        do_epilogue(p, (long)j, sm);
}

extern "C" void kernel_launch(void* const* d_in, const int* in_sizes, int n_in,
                              void* d_out, int out_size, void* d_ws, size_t ws_size,
                              hipStream_t stream)
{
    Params prm;
    prm.X     = (const float*)d_in[0];
    prm.posW  = (const float*)d_in[1];
    prm.posB  = (const float*)d_in[2];
    prm.pbias = (const float*)d_in[3];
    prm.spos  = (const float*)d_in[4];
    prm.lsc   = (const float*)d_in[5];
    prm.qW    = (const float*)d_in[6];
    prm.kW    = (const float*)d_in[7];
    prm.vW    = (const float*)d_in[8];
    prm.gates = (const float*)d_in[9];
    prm.rwp   = (const float*)d_in[10];
    prm.lnw   = (const float*)d_in[11];
    prm.lnb   = (const float*)d_in[12];

    char* ws = (char*)d_ws;
    size_t off = 0;
    prm.Xb  = (bf16*)(ws + off);   off += (size_t)Bb*Ss*Dd*2;
    prm.Wt  = (bf16*)(ws + off);   off += (size_t)3*Dd*Dd*2;
    prm.WpT = (bf16*)(ws + off);   off += (size_t)Ee*Dd*2;
    prm.QKV = (bf16*)(ws + off);   off += (size_t)2*2048*1024*2;  // Q,K only (V -> Vt)
    prm.Vt  = (bf16*)(ws + off);   off += (size_t)Bb*Dd*Ss*2;
    prm.Aav = (bf16*)(ws + off);   off += (size_t)Bb*Ss*Ss*2;
    prm.wh  = (__half*)(ws + off); off += (size_t)Bb*Ss*Nn*2;
    for (int h = 0; h < 4; ++h) { prm.qk[h] = (float*)(ws + off); off += (size_t)Bb*Ss*Ss*4; }
    for (int h = 0; h < 4; ++h) { prm.cb[h] = (float*)(ws + off); off += (size_t)Bb*Ss*Dd*4; }
    prm.bar = (unsigned*)(ws + off); off += 4096;
    prm.out = (float*)d_out;
    (void)ws_size;

    // barrier state must be zeroed every call (workspace is re-poisoned between runs)
    hipMemsetAsync(prm.bar, 0, 4096, stream);
    k_mega<<<NBLK, 256, 0, stream>>>(prm);
}

// Round 3
// 160.082 us; speedup vs baseline: 4.5598x; 2.6435x over previous
//
#include <hip/hip_runtime.h>
#include <hip/hip_bf16.h>
#include <hip/hip_fp16.h>

using bf16 = __hip_bfloat16;
typedef __attribute__((ext_vector_type(8))) short short8;
typedef __attribute__((ext_vector_type(4))) float f32x4;

static constexpr int Bb = 2, Ss = 1024, Dd = 1024, Ee = 64, Nn = 16;

struct Params {
    const float *X, *posW, *posB, *pbias, *spos, *lsc, *qW, *kW, *vW, *gates, *rwp, *lnw, *lnb;
    bf16 *Xb, *Wt, *WpT, *QKV, *Vt, *Aav;
    __half *wh;
    float *qk[4], *cb[4], *out;
};

__device__ __forceinline__ unsigned short f2bfr(float f) {
    __hip_bfloat16 h = __float2bfloat16(f);
    return *reinterpret_cast<unsigned short*>(&h);
}

#define GL_LDS(gp, lp) __builtin_amdgcn_global_load_lds( \
    (const __attribute__((address_space(1))) void*)(gp), \
    (__attribute__((address_space(3))) void*)(lp), 16, 0, 0)

// ---------- f32 -> bf16 transpose of a 64x64 tile ----------
__device__ __forceinline__ void do_transpose_f2b(
    const float* __restrict__ in, bf16* __restrict__ out,
    int R, int C, int bx, int by, char* sm)
{
    float (*tile)[65] = (float(*)[65])sm;
    int tx = threadIdx.x & 63, ty = threadIdx.x >> 6;
    int r0 = by * 64, c0 = bx * 64;
    #pragma unroll
    for (int i = 0; i < 16; ++i)
        tile[ty + i*4][tx] = in[(long)(r0 + ty + i*4)*C + c0 + tx];
    __syncthreads();
    #pragma unroll
    for (int i = 0; i < 16; ++i)
        out[(long)(c0 + ty + i*4)*R + r0 + tx] = __float2bfloat16(tile[tx][ty + i*4]);
    __syncthreads();
}

// ---------- 64x128 MFMA GEMM tile, BK=64, XOR-swizzled, 2-phase double-buffered ----------
// LDS: 2 buffers x (A 8KB + B 16KB) = 48 KB. One barrier per K-step (T3-minimum).
__device__ __forceinline__ void do_gemm64(
    const bf16* __restrict__ Ab, const bf16* __restrict__ Bw, float* __restrict__ C,
    int Nc, int m0, int n0, int kBeg, int kEnd, float scale, char* sm)
{
    int tid = threadIdx.x, wid = tid >> 6, lane = tid & 63;
    int wn = wid * 32, r16 = lane & 15, quad = lane >> 4;

    f32x4 acc[4][2];
    #pragma unroll
    for (int i = 0; i < 4; ++i)
        #pragma unroll
        for (int j = 0; j < 2; ++j)
            #pragma unroll
            for (int c = 0; c < 4; ++c) acc[i][j][c] = 0.f;

    const short* Ag = (const short*)Ab;
    const short* Bg = (const short*)Bw;

    int arow[2], akg[2], brow[4], bkg[4];
    #pragma unroll
    for (int j = 0; j < 2; ++j) {
        int c = tid + j*256; arow[j] = c >> 3; akg[j] = (c & 7) ^ (arow[j] & 7);
    }
    #pragma unroll
    for (int j = 0; j < 4; ++j) {
        int c = tid + j*256; brow[j] = c >> 3; bkg[j] = (c & 7) ^ (brow[j] & 7);
    }

    auto stage = [&](int k0, int cr) {
        short* sA = (short*)(sm + cr*24576);
        short* sB = (short*)(sm + cr*24576 + 8192);
        #pragma unroll
        for (int j = 0; j < 2; ++j)
            GL_LDS(Ag + (long)(m0 + arow[j])*1024 + k0 + akg[j]*8, sA + (tid + j*256)*8);
        #pragma unroll
        for (int j = 0; j < 4; ++j)
            GL_LDS(Bg + (long)(n0 + brow[j])*1024 + k0 + bkg[j]*8, sB + (tid + j*256)*8);
    };

    stage(kBeg, 0);
    __syncthreads();                  // prologue drain (compiler emits vmcnt(0) before barrier)
    int cur = 0;
    for (int k0 = kBeg; k0 < kEnd; k0 += 64) {
        if (k0 + 64 < kEnd) stage(k0 + 64, cur ^ 1);   // issue next tile early
        short* lA = (short*)(sm + cur*24576);
        short* lB = (short*)(sm + cur*24576 + 8192);
        #pragma unroll
        for (int kk = 0; kk < 2; ++kk) {
            int kc = kk*4 + quad;
            short8 af[4], bfv[2];
            #pragma unroll
            for (int i = 0; i < 4; ++i) {
                int r = i*16 + r16;
                af[i] = *(const short8*)(lA + r*64 + (kc ^ (r & 7))*8);
            }
            #pragma unroll
            for (int j = 0; j < 2; ++j) {
                int r = wn + j*16 + r16;
                bfv[j] = *(const short8*)(lB + r*64 + (kc ^ (r & 7))*8);
            }
            #pragma unroll
            for (int i = 0; i < 4; ++i)
                #pragma unroll
                for (int j = 0; j < 2; ++j)
                    acc[i][j] = __builtin_amdgcn_mfma_f32_16x16x32_bf16(af[i], bfv[j], acc[i][j], 0, 0, 0);
        }
        __syncthreads();              // drains next-tile loads AFTER compute (overlap)
        cur ^= 1;
    }

    #pragma unroll
    for (int i = 0; i < 4; ++i)
        #pragma unroll
        for (int j = 0; j < 2; ++j)
            #pragma unroll
            for (int rr = 0; rr < 4; ++rr)
                C[(long)(m0 + i*16 + quad*4 + rr)*Nc + n0 + wn + j*16 + r16] =
                    acc[i][j][rr] * scale;
}

// ---------- 128x128 MFMA GEMM tile, BK=64, XOR-swizzled, 2-phase double-buffered ----------
// LDS: 2 buffers x (A 16KB + B 16KB) = 64 KB.
template<int OUT_MODE>
__device__ __forceinline__ void do_gemm128(
    const bf16* __restrict__ Ab, const bf16* __restrict__ Bw, void* __restrict__ Cv,
    int Nc, int m0, int n0, char* sm)
{
    int tid = threadIdx.x, wid = tid >> 6, lane = tid & 63;
    int wm = (wid >> 1) * 64, wnn = (wid & 1) * 64;
    int r16 = lane & 15, quad = lane >> 4;

    f32x4 acc[4][4];
    #pragma unroll
    for (int i = 0; i < 4; ++i)
        #pragma unroll
        for (int j = 0; j < 4; ++j)
            #pragma unroll
            for (int c = 0; c < 4; ++c) acc[i][j][c] = 0.f;

    const short* Ag = (const short*)Ab;
    const short* Bg = (const short*)Bw;

    int rowc[4], kgc[4];
    #pragma unroll
    for (int j = 0; j < 4; ++j) {
        int c = tid + j*256; rowc[j] = c >> 3; kgc[j] = (c & 7) ^ (rowc[j] & 7);
    }

    auto stage = [&](int k0, int cr) {
        short* sA = (short*)(sm + cr*32768);
        short* sB = (short*)(sm + cr*32768 + 16384);
        #pragma unroll
        for (int j = 0; j < 4; ++j)
            GL_LDS(Ag + (long)(m0 + rowc[j])*1024 + k0 + kgc[j]*8, sA + (tid + j*256)*8);
        #pragma unroll
        for (int j = 0; j < 4; ++j)
            GL_LDS(Bg + (long)(n0 + rowc[j])*1024 + k0 + kgc[j]*8, sB + (tid + j*256)*8);
    };

    stage(0, 0);
    __syncthreads();
    int cur = 0;
    for (int k0 = 0; k0 < 1024; k0 += 64) {
        if (k0 + 64 < 1024) stage(k0 + 64, cur ^ 1);
        short* lA = (short*)(sm + cur*32768);
        short* lB = (short*)(sm + cur*32768 + 16384);
        #pragma unroll
        for (int kk = 0; kk < 2; ++kk) {
            int kc = kk*4 + quad;
            short8 af[4], bfv[4];
            #pragma unroll
            for (int i = 0; i < 4; ++i) {
                int r = wm + i*16 + r16;
                af[i] = *(const short8*)(lA + r*64 + (kc ^ (r & 7))*8);
            }
            #pragma unroll
            for (int j = 0; j < 4; ++j) {
                int r = wnn + j*16 + r16;
                bfv[j] = *(const short8*)(lB + r*64 + (kc ^ (r & 7))*8);
            }
            #pragma unroll
            for (int i = 0; i < 4; ++i)
                #pragma unroll
                for (int j = 0; j < 4; ++j)
                    acc[i][j] = __builtin_amdgcn_mfma_f32_16x16x32_bf16(af[i], bfv[j], acc[i][j], 0, 0, 0);
        }
        __syncthreads();
        cur ^= 1;
    }

    if (OUT_MODE == 1) {
        bf16* C = (bf16*)Cv;
        #pragma unroll
        for (int i = 0; i < 4; ++i)
            #pragma unroll
            for (int j = 0; j < 4; ++j)
                #pragma unroll
                for (int rr = 0; rr < 4; ++rr)
                    C[(long)(m0 + wm + i*16 + quad*4 + rr)*Nc + n0 + wnn + j*16 + r16] =
                        __float2bfloat16(acc[i][j][rr]);
    } else {
        __syncthreads();
        bf16 (*lt)[132] = (bf16(*)[132])sm;   // 33792 B, reuses staging LDS (loop done)
        #pragma unroll
        for (int i = 0; i < 4; ++i)
            #pragma unroll
            for (int j = 0; j < 4; ++j)
                #pragma unroll
                for (int rr = 0; rr < 4; ++rr)
                    lt[wnn + j*16 + r16][wm + i*16 + quad*4 + rr] =
                        __float2bfloat16(acc[i][j][rr]);
        __syncthreads();
        bf16* Vb = (bf16*)Cv + (long)(m0 >> 10) * Dd * Ss;
        int s0 = m0 & (Ss - 1);
        int colBase = wid * 32 + (lane >> 4);
        int idx = (lane & 15) * 8;
        #pragma unroll
        for (int it = 0; it < 8; ++it) {
            int col = colBase + it * 4;
            ushort4 v0 = *(const ushort4*)&lt[col][idx];
            ushort4 v1 = *(const ushort4*)&lt[col][idx + 4];
            *(ushort4*)(Vb + (long)(n0 + col)*Ss + s0 + idx)     = v0;
            *(ushort4*)(Vb + (long)(n0 + col)*Ss + s0 + idx + 4) = v1;
        }
    }
}

// ---------- pos GEMM (64 rows) + tanh/bias + splat influence -> wh (half) ----------
// 2-phase double-buffered staging: buffers at sm[0..16K); P/sp above.
__device__ __forceinline__ void do_pos(const Params& p, int m0, char* sm)
{
    float (*P)[65]  = (float(*)[65])(sm + 16384);
    float (*sp)[65] = (float(*)[65])(sm + 16384 + 64*65*4);

    int tid = threadIdx.x, wid = tid >> 6, lane = tid & 63;
    int r16 = lane & 15, quad = lane >> 4;

    for (int idx = tid; idx < 16*64; idx += 256)
        sp[idx >> 6][idx & 63] = p.spos[idx];

    f32x4 acc[4];
    #pragma unroll
    for (int j = 0; j < 4; ++j)
        #pragma unroll
        for (int c = 0; c < 4; ++c) acc[j][c] = 0.f;

    int ra = tid >> 2, ka = (tid & 3) * 8;
    const short* Ag = (const short*)p.Xb;
    const short* Bg = (const short*)p.WpT;

    auto stage = [&](int k0, int cr) {
        short* sA = (short*)(sm + cr*8192);
        short* sB = (short*)(sm + cr*8192 + 4096);
        GL_LDS(Ag + (long)(m0+ra)*1024 + k0 + ka, sA + tid*8);
        GL_LDS(Bg + (long)ra*1024 + k0 + ka,      sB + tid*8);
    };

    stage(0, 0);
    __syncthreads();
    int cur = 0;
    for (int k0 = 0; k0 < Dd; k0 += 32) {
        if (k0 + 32 < Dd) stage(k0 + 32, cur ^ 1);
        short* lA = (short*)(sm + cur*8192);
        short* lB = (short*)(sm + cur*8192 + 4096);
        short8 af = *(const short8*)(lA + (wid*16 + r16)*32 + quad*8);
        #pragma unroll
        for (int j = 0; j < 4; ++j) {
            short8 bfv = *(const short8*)(lB + (j*16 + r16)*32 + quad*8);
            acc[j] = __builtin_amdgcn_mfma_f32_16x16x32_bf16(af, bfv, acc[j], 0, 0, 0);
        }
        __syncthreads();
        cur ^= 1;
    }

    #pragma unroll
    for (int j = 0; j < 4; ++j)
        #pragma unroll
        for (int rr = 0; rr < 4; ++rr) {
            int rl  = wid*16 + quad*4 + rr;
            int col = j*16 + r16;
            int srow = (m0 + rl) & (Ss - 1);
            P[rl][col] = tanhf(acc[j][rr] + p.posB[col]) + p.pbias[srow*Ee + col];
        }
    __syncthreads();

    int n  = tid & 15;
    int rb = (tid >> 4) * 4;
    float sc = __expf(p.lsc[n]);
    sc = fminf(fmaxf(sc, 0.3f), 2.0f);
    float inv2 = -0.5f / (sc * sc);
    #pragma unroll
    for (int rr = 0; rr < 4; ++rr) {
        int row = rb + rr;
        float d2 = 0.f;
        #pragma unroll 16
        for (int e = 0; e < 64; ++e) {
            float df = P[row][e] - sp[n][e];
            d2 += df * df;
        }
        float infl = fmaxf(__expf(d2 * inv2), 0.01f);
        p.wh[(long)(m0 + row)*Nn + n] = __float2half(infl);
    }
}

// ========== K1: weight transposes + posW^T + X cast ==========
__global__ __launch_bounds__(256) void k_prep(Params p)
{
    __shared__ __align__(16) char sm[64*65*4];
    int z = blockIdx.z;
    if (z < 3) {
        const float* w = (z == 0) ? p.qW : (z == 1) ? p.kW : p.vW;
        do_transpose_f2b(w, p.Wt + (long)z*Dd*Dd, Dd, Dd, blockIdx.x, blockIdx.y, sm);
    } else if (blockIdx.x == 0) {
        do_transpose_f2b(p.posW, p.WpT, Dd, Ee, 0, blockIdx.y, sm);
    } else {
        int job = blockIdx.y * 15 + (blockIdx.x - 1);     // 0..239
        const float4* src = (const float4*)p.X;
        ushort4* dst = (ushort4*)p.Xb;
        for (int idx = job*256 + (int)threadIdx.x; idx < Bb*Ss*Dd/4; idx += 240*256) {
            float4 v = src[idx];
            ushort4 y;
            y.x = f2bfr(v.x); y.y = f2bfr(v.y); y.z = f2bfr(v.z); y.w = f2bfr(v.w);
            dst[idx] = y;
        }
    }
}

// ========== K2: QKV GEMM 128x128 (384 jobs; V transposed) + pos (32 jobs) ==========
__global__ __launch_bounds__(256) void k_qkv_pos(Params p)
{
    __shared__ __align__(16) char sm[65536];
    int job = blockIdx.x;
    if (job < 384) {
        int z = job >> 7, t = job & 127;
        int bm = t >> 3, bn = t & 7;
        if (z < 2)
            do_gemm128<1>(p.Xb, p.Wt + (long)z*Dd*Dd, p.QKV + (long)z*2048*1024,
                          Dd, bm*128, bn*128, sm);
        else
            do_gemm128<2>(p.Xb, p.Wt + (long)2*Dd*Dd, p.Vt,
                          Dd, bm*128, bn*128, sm);
    } else {
        do_pos(p, (job - 384)*64, sm);
    }
}

// ========== K3: qk split-K=4 (576 jobs) ==========
__global__ __launch_bounds__(256) void k_qkt(Params p)
{
    __shared__ __align__(16) char sm[49152];
    int job = blockIdx.x;
    int h = job & 3, pairIdx = job >> 2;
    int b = pairIdx / 72, t = pairIdx % 72;
    int acc = 0, bm = 0, bn = 0;
    #pragma unroll
    for (int u = 0; u < 16; ++u) {
        int c = (u >> 1) + 1;
        if (t < acc + c) { bm = u; bn = t - acc; break; }
        acc += c;
    }
    const bf16* Qb = p.QKV + (long)b*Ss*Dd;
    const bf16* Kb = p.QKV + (long)2048*1024 + (long)b*Ss*Dd;
    float* dst = p.qk[h] + (long)b*Ss*Ss;
    do_gemm64(Qb, Kb, dst, Ss, bm*64, bn*128, h*256, h*256 + 256, 0.03125f, sm);
}

// ========== K4: softmax + gated average over 4 qk partials ==========
// Pass-1 caches the summed f32 row in LDS (pass-2: zero global re-reads, identical values).
// Pass-2/store clipped to jLim=(i|63)+1 — the only region AV ever reads.
__global__ __launch_bounds__(256) void k_softmax(Params p)
{
    __shared__ __align__(16) char sm[36864 + 256 + 16384];
    __half2 (*wt)[9] = (__half2(*)[9])sm;
    float (*wi4)[16] = (float(*)[16])(sm + 36864);
    float (*qc)[Ss]  = (float(*)[Ss])(sm + 36864 + 256);

    int base = blockIdx.x * 4, b = blockIdx.y;
    int tid = threadIdx.x, wid = tid >> 6, lane = tid & 63;
    int imax = base + 3;

    const __half*  whb  = p.wh + (long)b*Ss*Nn;
    const __half2* whb2 = (const __half2*)whb;

    for (int j = tid; j <= imax; j += 256) {
        #pragma unroll
        for (int h = 0; h < 8; ++h)
            wt[j][h] = whb2[j*8 + h];
    }
    if (tid < 64) wi4[tid >> 4][tid & 15] =
        __half2float(whb[(long)(base + (tid >> 4))*16 + (tid & 15)]);
    __syncthreads();

    int i = base + wid;
    long roff = ((long)b*Ss + i)*Ss;
    const float* q0 = p.qk[0] + roff;
    const float* q1 = p.qk[1] + roff;
    const float* q2 = p.qk[2] + roff;
    const float* q3 = p.qk[3] + roff;
    bf16* arow      = p.Aav + roff;

    float wiR[16], l[16];
    #pragma unroll
    for (int n = 0; n < 16; ++n) { wiR[n] = wi4[wid][n]; l[n] = 0.f; }

    for (int j = lane; j <= i; j += 64) {
        float q = (q0[j] + q1[j]) + (q2[j] + q3[j]);
        qc[wid][j] = q;
        #pragma unroll
        for (int h = 0; h < 8; ++h) {
            float2 f = __half22float2(wt[j][h]);
            l[2*h]     += __expf(wiR[2*h]     * f.x * q);
            l[2*h + 1] += __expf(wiR[2*h + 1] * f.y * q);
        }
    }
    #pragma unroll
    for (int n = 0; n < 16; ++n)
        #pragma unroll
        for (int off = 32; off > 0; off >>= 1)
            l[n] += __shfl_xor(l[n], off);

    float coef[16];
    #pragma unroll
    for (int n = 0; n < 16; ++n) {
        float g  = p.gates[n];
        float sg = 1.f / (1.f + __expf(-g));
        coef[n]  = sg / (16.f * l[n]);
    }

    int jLim = (i | 63) + 1;   // AV reads row i only for k < ((i>>6)+1)*64
    for (int j = lane; j < jLim; j += 64) {
        float a = 0.f;
        if (j <= i) {
            float q = qc[wid][j];
            #pragma unroll
            for (int h = 0; h < 8; ++h) {
                float2 f = __half22float2(wt[j][h]);
                a += coef[2*h]     * __expf(wiR[2*h]     * f.x * q);
                a += coef[2*h + 1] * __expf(wiR[2*h + 1] * f.y * q);
            }
        }
        arow[j] = __float2bfloat16(a);
    }
}

// ========== K5: AV GEMM split-K<=4 (640 jobs) ==========
__global__ __launch_bounds__(256) void k_av(Params p)
{
    __shared__ __align__(16) char sm[49152];
    int job = blockIdx.x;
    int b  = job / 320;
    int r  = job % 320;
    int bn = r / 40;
    int u  = r % 40;
    int acc = 0, bm = 0, h = 0;
    #pragma unroll
    for (int m = 0; m < 16; ++m) {
        int c = (m >> 2) + 1;
        if (u < acc + c) { bm = m; h = u - acc; break; }
        acc += c;
    }
    int kBeg = h * 256;
    int kEnd = (bm + 1) * 64; if (kEnd > kBeg + 256) kEnd = kBeg + 256;

    const bf16* Ab = p.Aav + (long)b*Ss*Ss;
    const bf16* Bw = p.Vt + (long)b*Dd*Ss;
    float* dst = p.cb[h] + (long)b*Ss*Dd;
    do_gemm64(Ab, Bw, dst, Dd, bm*64, bn*128, kBeg, kEnd, 1.f, sm);
}

// ========== K6: residual + LayerNorm over 4 cb partials ==========
__global__ __launch_bounds__(256) void k_epilogue(Params p)
{
    __shared__ float rs[4], rq[4];
    long row = blockIdx.x;
    int tid = threadIdx.x, wid = tid >> 6, lane = tid & 63;
    float rw = 1.f / (1.f + __expf(-p.rwp[0]));

    int s = (int)(row & (Ss - 1));
    float4 c = ((const float4*)(p.cb[0] + row*Dd))[tid];
    #pragma unroll
    for (int h = 1; h < 4; ++h) {
        if (s >= h*256) {
            float4 ch = ((const float4*)(p.cb[h] + row*Dd))[tid];
            c.x += ch.x; c.y += ch.y; c.z += ch.z; c.w += ch.w;
        }
    }
    float4 xv = ((const float4*)(p.X + row*Dd))[tid];

    float o[4];
    o[0] = rw * xv.x + (1.f - rw) * c.x;
    o[1] = rw * xv.y + (1.f - rw) * c.y;
    o[2] = rw * xv.z + (1.f - rw) * c.z;
    o[3] = rw * xv.w + (1.f - rw) * c.w;

    float sm1 = o[0] + o[1] + o[2] + o[3];
    float sq  = o[0]*o[0] + o[1]*o[1] + o[2]*o[2] + o[3]*o[3];
    #pragma unroll
    for (int off = 32; off > 0; off >>= 1) { sm1 += __shfl_xor(sm1, off); sq += __shfl_xor(sq, off); }
    if (lane == 0) { rs[wid] = sm1; rq[wid] = sq; }
    __syncthreads();
    sm1 = rs[0] + rs[1] + rs[2] + rs[3];
    sq  = rq[0] + rq[1] + rq[2] + rq[3];
    float mu  = sm1 * (1.f/1024.f);
    float var = sq * (1.f/1024.f) - mu*mu;
    float inv = rsqrtf(var + 1e-5f);

    float4 lw = ((const float4*)p.lnw)[tid];
    float4 lb = ((const float4*)p.lnb)[tid];
    float4 y;
    y.x = (o[0] - mu)*inv*lw.x + lb.x;
    y.y = (o[1] - mu)*inv*lw.y + lb.y;
    y.z = (o[2] - mu)*inv*lw.z + lb.z;
    y.w = (o[3] - mu)*inv*lw.w + lb.w;
    ((float4*)(p.out + row*Dd))[tid] = y;
}

extern "C" void kernel_launch(void* const* d_in, const int* in_sizes, int n_in,
                              void* d_out, int out_size, void* d_ws, size_t ws_size,
                              hipStream_t stream)
{
    Params prm;
    prm.X     = (const float*)d_in[0];
    prm.posW  = (const float*)d_in[1];
    prm.posB  = (const float*)d_in[2];
    prm.pbias = (const float*)d_in[3];
    prm.spos  = (const float*)d_in[4];
    prm.lsc   = (const float*)d_in[5];
    prm.qW    = (const float*)d_in[6];
    prm.kW    = (const float*)d_in[7];
    prm.vW    = (const float*)d_in[8];
    prm.gates = (const float*)d_in[9];
    prm.rwp   = (const float*)d_in[10];
    prm.lnw   = (const float*)d_in[11];
    prm.lnb   = (const float*)d_in[12];

    char* ws = (char*)d_ws;
    size_t off = 0;
    prm.Xb  = (bf16*)(ws + off);   off += (size_t)Bb*Ss*Dd*2;
    prm.Wt  = (bf16*)(ws + off);   off += (size_t)3*Dd*Dd*2;
    prm.WpT = (bf16*)(ws + off);   off += (size_t)Ee*Dd*2;
    prm.QKV = (bf16*)(ws + off);   off += (size_t)2*2048*1024*2;  // Q,K only (V -> Vt)
    prm.Vt  = (bf16*)(ws + off);   off += (size_t)Bb*Dd*Ss*2;
    prm.Aav = (bf16*)(ws + off);   off += (size_t)Bb*Ss*Ss*2;
    prm.wh  = (__half*)(ws + off); off += (size_t)Bb*Ss*Nn*2;
    for (int h = 0; h < 4; ++h) { prm.qk[h] = (float*)(ws + off); off += (size_t)Bb*Ss*Ss*4; }
    for (int h = 0; h < 4; ++h) { prm.cb[h] = (float*)(ws + off); off += (size_t)Bb*Ss*Dd*4; }
    prm.out = (float*)d_out;
    (void)ws_size;

    k_prep    <<<dim3(16,16,4), 256, 0, stream>>>(prm);
    k_qkv_pos <<<416,            256, 0, stream>>>(prm);
    k_qkt     <<<576,            256, 0, stream>>>(prm);
    k_softmax <<<dim3(256, 2),   256, 0, stream>>>(prm);
    k_av      <<<640,            256, 0, stream>>>(prm);
    k_epilogue<<<2048,           256, 0, stream>>>(prm);
}